// Round 1
// baseline (2343.728 us; speedup 1.0000x reference)
//
#include <hip/hip_runtime.h>
#include <cstdint>
#include <cstddef>

#define BB 512
#define TT 1024
#define FF 128
#define HH 128
#define AA 16

// One block per batch element. 128 threads = 2 waves; thread tid owns
// row h=tid of the hidden state (mem1[h], mem2[h]) and W1 row h in VGPRs.
// W2^T / W3^T staged in LDS (74 KB dynamic -> 2 blocks/CU).
__global__ __launch_bounds__(128, 1) void dsqn_fused(
    const float* __restrict__ X,      // (B,T,F)
    const float* __restrict__ hid,    // (B,1,2,H)
    const float* __restrict__ W1,     // (H,F)
    const float* __restrict__ b1,     // (H)
    const float* __restrict__ beta1,  // (H)
    const float* __restrict__ W2,     // (H,H)
    const float* __restrict__ b2,     // (H)
    const float* __restrict__ beta2,  // (H)
    const float* __restrict__ W3,     // (A,H)
    const float* __restrict__ b3,     // (A)
    float* __restrict__ out)          // (B,T,A)
{
    extern __shared__ float lds[];
    float* W2T = lds;                         // [h][j] 128*128 floats
    float* W3T = lds + HH * HH;               // [j][a] 128*16 floats
    float* partials = W3T + HH * AA;          // [128]
    unsigned* masksW = (unsigned*)(partials + 128);  // [8] spike masks

    const int tid = threadIdx.x;
    const int b = blockIdx.x;

    // Stage W2^T: cur2[j] = sum_h spk1[h] * W2[j,h]  -> W2T[h][j], lane-consecutive j.
    for (int i = tid; i < HH * HH; i += 128) {
        int j = i >> 7, h = i & 127;
        W2T[h * HH + j] = W2[i];
    }
    // Stage W3^T: out[a] = sum_j spk2[j] * W3[a,j] -> W3T[j][a].
    for (int i = tid; i < AA * HH; i += 128) {
        int a = i >> 7, j = i & 127;
        W3T[j * AA + a] = W3[i];
    }

    // W1 row h in registers (32 float4 = 128 VGPRs).
    float4 w1q[32];
    {
        const float4* w1p = (const float4*)(W1 + tid * FF);
        #pragma unroll
        for (int q = 0; q < 32; ++q) w1q[q] = w1p[q];
    }

    float mem1 = hid[b * 2 * HH + tid];
    float mem2 = hid[b * 2 * HH + HH + tid];
    const float b1h = b1[tid];
    const float b2h = b2[tid];
    const float bt1 = fminf(fmaxf(beta1[tid], 0.f), 1.f);
    const float bt2 = fminf(fmaxf(beta2[tid], 0.f), 1.f);
    const float b3a = (tid < AA) ? b3[tid] : 0.f;

    const float* xrow = X + (size_t)b * TT * FF;
    float* orow = out + (size_t)b * TT * AA;

    __syncthreads();

    for (int t = 0; t < TT; ++t) {
        // ---- cur1[h] = x . W1[h,:] + b1[h] ----
        // xrow is wave-uniform -> x loads should scalarize; FMAs are s*v.
        const float4* x4 = (const float4*)xrow;
        float s0 = 0.f, s1 = 0.f, s2 = 0.f, s3 = 0.f;
        #pragma unroll
        for (int q = 0; q < 32; ++q) {
            float4 xv = x4[q];
            s0 = fmaf(xv.x, w1q[q].x, s0);
            s1 = fmaf(xv.y, w1q[q].y, s1);
            s2 = fmaf(xv.z, w1q[q].z, s2);
            s3 = fmaf(xv.w, w1q[q].w, s3);
        }
        const float cur1 = ((s0 + s1) + (s2 + s3)) + b1h;

        // ---- LIF1: reset uses OLD mem ----
        const float r1 = (mem1 > 1.0f) ? 1.0f : 0.0f;
        mem1 = bt1 * mem1 + cur1 - r1;
        const int sp1 = (mem1 - 1.0f) > 0.0f;

        unsigned long long bal1 = __ballot(sp1);
        if ((tid & 63) == 0) {
            masksW[(tid >> 6) * 2]     = (unsigned)(bal1 & 0xFFFFFFFFull);
            masksW[(tid >> 6) * 2 + 1] = (unsigned)(bal1 >> 32);
        }
        __syncthreads();  // B1: spk1 masks visible

        // ---- cur2[j] = b2[j] + sum over active h of W2T[h][j] ----
        unsigned mw0 = __builtin_amdgcn_readfirstlane(masksW[0]);
        unsigned mw1 = __builtin_amdgcn_readfirstlane(masksW[1]);
        unsigned mw2 = __builtin_amdgcn_readfirstlane(masksW[2]);
        unsigned mw3 = __builtin_amdgcn_readfirstlane(masksW[3]);

        float c2a = b2h, c2b = 0.f;
        while (mw0) { int h = __builtin_ctz(mw0); mw0 &= mw0 - 1; c2a += W2T[h * HH + tid]; }
        while (mw1) { int h = __builtin_ctz(mw1); mw1 &= mw1 - 1; c2b += W2T[(32 + h) * HH + tid]; }
        while (mw2) { int h = __builtin_ctz(mw2); mw2 &= mw2 - 1; c2a += W2T[(64 + h) * HH + tid]; }
        while (mw3) { int h = __builtin_ctz(mw3); mw3 &= mw3 - 1; c2b += W2T[(96 + h) * HH + tid]; }
        const float cur2 = c2a + c2b;

        // ---- LIF2 ----
        const float r2 = (mem2 > 1.0f) ? 1.0f : 0.0f;
        mem2 = bt2 * mem2 + cur2 - r2;
        const int sp2 = (mem2 - 1.0f) > 0.0f;

        unsigned long long bal2 = __ballot(sp2);
        if ((tid & 63) == 0) {
            masksW[4 + (tid >> 6) * 2] = (unsigned)(bal2 & 0xFFFFFFFFull);
            masksW[5 + (tid >> 6) * 2] = (unsigned)(bal2 >> 32);
        }
        __syncthreads();  // B2: spk2 masks visible

        // ---- out partials: 8 groups x 16 lanes, group g covers j in [16g,16g+16) ----
        {
            const int g = tid >> 4, a = tid & 15;
            unsigned word = masksW[4 + (g >> 1)];
            unsigned chunk = (word >> ((g & 1) * 16)) & 0xFFFFu;
            const int jbase = g * 16;
            float p = 0.f;
            while (chunk) {
                int j = jbase + __builtin_ctz(chunk);
                chunk &= chunk - 1;
                p += W3T[j * AA + a];
            }
            partials[tid] = p;
        }
        __syncthreads();  // B3: partials visible

        if (tid < AA) {
            float o = b3a;
            #pragma unroll
            for (int g = 0; g < 8; ++g) o += partials[g * 16 + tid];
            orow[t * AA + tid] = o;
        }
        // No 4th barrier needed: next step's first LDS writes (masksW[0..3])
        // are ordered after B2/B3 of this step relative to all readers.
        xrow += FF;
    }
}

extern "C" void kernel_launch(void* const* d_in, const int* in_sizes, int n_in,
                              void* d_out, int out_size, void* d_ws, size_t ws_size,
                              hipStream_t stream) {
    const float* X     = (const float*)d_in[0];
    const float* hid   = (const float*)d_in[1];
    const float* W1    = (const float*)d_in[2];
    const float* b1    = (const float*)d_in[3];
    const float* beta1 = (const float*)d_in[4];
    const float* W2    = (const float*)d_in[5];
    const float* b2    = (const float*)d_in[6];
    const float* beta2 = (const float*)d_in[7];
    const float* W3    = (const float*)d_in[8];
    const float* b3    = (const float*)d_in[9];
    float* out = (float*)d_out;

    const size_t shmem = (size_t)(HH * HH + HH * AA + 128) * sizeof(float) + 8 * sizeof(unsigned);
    // 74,272 B dynamic LDS (> 64 KB default cap) -> raise the attribute.
    (void)hipFuncSetAttribute((const void*)dsqn_fused,
                              hipFuncAttributeMaxDynamicSharedMemorySize, (int)shmem);

    dsqn_fused<<<BB, 128, shmem, stream>>>(X, hid, W1, b1, beta1, W2, b2, beta2, W3, b3, out);
}